// Round 12
// baseline (759.852 us; speedup 1.0000x reference)
//
#include <hip/hip_runtime.h>
#include <hip/hip_bf16.h>
#include <stdint.h>

#define T_ROWS 131072
#define GCNT   64
#define KDIM   1024
#define NDIM   512
#define BM     256
#define BN     128
#define BK     64
#define KTILES (KDIM / BK)     // 16
#define MT_MAX 640             // upper bound on 256-row tiles (actual ~550)
#define NBLK   (MT_MAX * 4)    // 2560 blocks, /8 = 320 (XCD swizzle exact)
#define FB_NBLK (1088 * 4)     // fallback kernel grid (128-row tiles)

typedef __attribute__((ext_vector_type(4))) float f32x4;
typedef __attribute__((ext_vector_type(8))) short s16x8;
typedef __attribute__((ext_vector_type(4))) short s16x4;
typedef __attribute__((address_space(3))) unsigned int lds_u32;
typedef const __attribute__((address_space(1))) unsigned int gbl_u32;

static __device__ __forceinline__ short f2bf(float f) {
  __hip_bfloat16 h = __float2bfloat16(f);
  return __builtin_bit_cast(short, h);
}

// ---------------------------------------------------------------------------
// Pre-pass: b [G][K][N] fp32 -> bt: per (g, nt128, kt) 16KB bf16 tile images,
// layout [G][4][16][16384B]. Image byte for B[k][n] (k in [0,64), n in
// [0,128)):  n*128 + (((k>>3) ^ (n&7))<<4) + (k&7)*2   (bank swizzle baked).
// ---------------------------------------------------------------------------
__global__ __launch_bounds__(256) void bt_kernel(const float* __restrict__ b,
                                                 char* __restrict__ bt) {
  __shared__ short lt[64 * 130];
  int bid = blockIdx.x;               // g*64 + nt*16 + kt
  int kt = bid & 15, nt = (bid >> 4) & 3, g = bid >> 6;
  int t = threadIdx.x;
  const float* src = b + ((size_t)(g * KDIM + kt * BK)) * NDIM + nt * 128;
#pragma unroll
  for (int i = 0; i < 32; i++) {
    int idx = i * 256 + t;
    int kk = idx >> 7, nn = idx & 127;
    lt[kk * 130 + nn] = f2bf(src[(size_t)kk * NDIM + nn]);
  }
  __syncthreads();
  char* dst = bt + ((size_t)bid << 14);
#pragma unroll
  for (int j = 0; j < 4; j++) {
    int chunk = j * 256 + t;
    int n = chunk >> 3;
    int slot = (chunk & 7) ^ (n & 7);
    s16x8 v;
#pragma unroll
    for (int i = 0; i < 8; i++) v[i] = lt[(slot * 8 + i) * 130 + n];
    *(s16x8*)(dst + (size_t)chunk * 16) = v;
  }
}

// ---------------------------------------------------------------------------
// High-intensity grouped GEMM: 256x128 tile, 4 waves (2Mx2N), each wave owns
// a 128x64 output (64 MFMA per 24 ds_read_b128 per tile -- LDS and MFMA
// pipes balanced). BK=64; A single-buffered 32 KB; B double-buffered
// 2x16 KB via pre-swizzled bt DMA. 64 KB LDS -> 2 blocks/CU.
// r11's counted-wait structure, unchanged:
//   stageB(kt+1->nxt) | writeA(kt) [cvt auto-waits vmcnt(4): retires
//   A(kt)+B(kt), keeps B(kt+1) flying] | loadA(kt+1) | lgkm0+bar |
//   compute(cur) | bar.  No explicit vmcnt in the loop.
// ---------------------------------------------------------------------------
__global__ __launch_bounds__(256, 2) void gemm4(
    const float* __restrict__ a, const char* __restrict__ bt,
    const int* __restrict__ sizes, const int* __restrict__ offs,
    float* __restrict__ out) {
  __shared__ __align__(16) short lds_a[BM * BK];        // 32 KB, single
  __shared__ __align__(16) char lds_b[2][BN * BK * 2];  // 2 x 16 KB

  int bid0 = blockIdx.x;
  int bid = (bid0 & 7) * (NBLK / 8) + (bid0 >> 3);  // XCD-chunked swizzle
  int bn = bid & 3;      // bn fastest: 4 blocks sharing an A panel adjacent
  int tm = bid >> 2;

  // group scan: 256-row tiles over 128-padded sizes
  int g = -1, m_loc = 0, base = 0;
#pragma unroll
  for (int i = 0; i < GCNT; i++) {
    int ps = (sizes[i] + 127) & ~127;
    int tg = (ps + 255) >> 8;
    if (tm >= base && tm < base + tg) { g = i; m_loc = (tm - base) << 8; }
    base += tg;
  }
  if (g < 0) return;
  int size = sizes[g], off = offs[g], valid = size - m_loc;

  int t = threadIdx.x, lane = t & 63, wid = t >> 6;
  int wm = wid >> 1, wn = wid & 1, lr = lane & 15, q = lane >> 4;

  // A staging: thread t owns rows i*16 + (t>>4) (i=0..15), 16B chunk (t&15)
  int r0 = t >> 4, c16 = t & 15;
  int aoff[16];
#pragma unroll
  for (int i = 0; i < 16; i++) {
    int row = off + m_loc + i * 16 + r0;
    if (row >= T_ROWS) row = T_ROWS - 1;  // junk rows masked at store
    aoff[i] = row * KDIM + c16 * 4;
  }
  int a_wbyte = r0 * 128 + (((c16 >> 1) ^ (r0 & 7)) << 4) + (c16 & 1) * 8;

  const char* btimg = bt + ((size_t)((g << 6) + (bn << 4)) << 14);

  f32x4 acc[8][4];
#pragma unroll
  for (int i = 0; i < 8; i++)
#pragma unroll
    for (int j = 0; j < 4; j++) acc[i][j] = (f32x4){0.f, 0.f, 0.f, 0.f};
  f32x4 va[16];   // single recycled A fp32 bank (issued + consumed per tile)

  auto loadA = [&](int kt) {
#pragma unroll
    for (int i = 0; i < 16; i++)
      va[i] = *(const f32x4*)(a + aoff[i] + kt * BK);
  };
  auto writeA = [&]() {  // cvt auto-waits counted vmcnt on va
    char* db = (char*)lds_a + a_wbyte;
#pragma unroll
    for (int i = 0; i < 16; i++) {
      s16x4 v;
#pragma unroll
      for (int e = 0; e < 4; e++) v[e] = f2bf(va[i][e]);
      *(s16x4*)(db + i * 2048) = v;   // row step 16 -> 16*128 bytes
    }
  };
  auto stageB = [&](int kt, int c) {
#pragma unroll
    for (int i = 0; i < 4; i++) {
      int wc = wid * 4 + i;                 // wave-uniform 1KB chunk, 0..15
      int cc = wc * 64 + lane;
      const char* gsrc = btimg + ((size_t)kt << 14) + (size_t)cc * 16;
      __builtin_amdgcn_global_load_lds(
          (gbl_u32*)gsrc, (lds_u32*)((char*)lds_b[c] + wc * 1024), 16, 0, 0);
    }
  };
  auto compute = [&](int c) {
#pragma unroll
    for (int ks = 0; ks < 2; ks++) {
      s16x8 af[8], bf[4];
#pragma unroll
      for (int fm = 0; fm < 8; fm++) {
        int row = wm * 128 + fm * 16 + lr;
        int slot = (ks * 4 + q) ^ (row & 7);
        af[fm] = *(const s16x8*)((const char*)lds_a + row * 128 + slot * 16);
      }
#pragma unroll
      for (int fn = 0; fn < 4; fn++) {
        int n = wn * 64 + fn * 16 + lr;
        int slot = (ks * 4 + q) ^ (n & 7);
        bf[fn] = *(const s16x8*)((const char*)lds_b[c] + n * 128 + slot * 16);
      }
      __builtin_amdgcn_s_setprio(1);
#pragma unroll
      for (int fm = 0; fm < 8; fm++)
#pragma unroll
        for (int fn = 0; fn < 4; fn++)
          acc[fm][fn] = __builtin_amdgcn_mfma_f32_16x16x32_bf16(
              af[fm], bf[fn], acc[fm][fn], 0, 0, 0);
      __builtin_amdgcn_s_setprio(0);
    }
  };

  // prologue: B(0) DMA first (oldest), then A(0) loads
  stageB(0, 0);
  __builtin_amdgcn_sched_barrier(0);
  loadA(0);

  // uniform loop kt = 0..14
  for (int kt = 0; kt < KTILES - 1; kt++) {
    int cur = kt & 1, nxt = cur ^ 1;
    stageB(kt + 1, nxt);                 // 4 DMA into the dead B buffer
    __builtin_amdgcn_sched_barrier(0);
    writeA();                            // counted vmcnt: retires A(kt)+B(kt)
    loadA(kt + 1);                       // 16 loads, fly across compute
    asm volatile("s_waitcnt lgkmcnt(0)" ::: "memory");
    __builtin_amdgcn_sched_barrier(0);
    __builtin_amdgcn_s_barrier();        // publish lds_a + B(kt) ready
    compute(cur);
    __builtin_amdgcn_sched_barrier(0);
    __builtin_amdgcn_s_barrier();        // frees lds_a, lds_b[nxt]
  }
  // peeled kt = 15
  writeA();
  asm volatile("s_waitcnt lgkmcnt(0)" ::: "memory");
  __builtin_amdgcn_sched_barrier(0);
  __builtin_amdgcn_s_barrier();
  compute(1);

  // epilogue: D frag col = lane&15, row = (lane>>4)*4 + j; masked rows
  size_t orow0 = (size_t)(off + m_loc);
#pragma unroll
  for (int fm = 0; fm < 8; fm++) {
#pragma unroll
    for (int j = 0; j < 4; j++) {
      int rm = wm * 128 + fm * 16 + q * 4 + j;
      if (rm < valid) {
        float* orow = out + (orow0 + rm) * NDIM + bn * BN + wn * 64 + lr;
#pragma unroll
        for (int fn = 0; fn < 4; fn++) orow[fn * 16] = acc[fm][fn][j];
      }
    }
  }
}

// ---------------------------------------------------------------------------
// Fallback (no workspace): r11 2-phase 128x128 kernel, B transposed in-kernel.
// ---------------------------------------------------------------------------
__global__ __launch_bounds__(256, 2) void gemm_fb(
    const float* __restrict__ a, const float* __restrict__ b,
    const int* __restrict__ sizes, const int* __restrict__ offs,
    float* __restrict__ out) {
  __shared__ __align__(16) short lds_a2[2][128 * BK];
  __shared__ __align__(16) char lds_b2[2][128 * BK * 2];

  int bid0 = blockIdx.x;
  int bid = (bid0 & 7) * (FB_NBLK / 8) + (bid0 >> 3);
  int bn = bid & 3;
  int tm = bid >> 2;

  int g = -1, m_loc = 0, base = 0;
#pragma unroll
  for (int i = 0; i < GCNT; i++) {
    int tg = ((sizes[i] + 127) & ~127) >> 7;
    if (tm >= base && tm < base + tg) { g = i; m_loc = (tm - base) << 7; }
    base += tg;
  }
  if (g < 0) return;
  int size = sizes[g], off = offs[g], valid = size - m_loc;

  int t = threadIdx.x, lane = t & 63, wid = t >> 6;
  int wm = wid >> 1, wn = wid & 1, lr = lane & 15, q = lane >> 4;

  int r0 = t >> 4, c16 = t & 15;
  int aoff[8];
#pragma unroll
  for (int i = 0; i < 8; i++) {
    int row = off + m_loc + i * 16 + r0;
    if (row >= T_ROWS) row = T_ROWS - 1;
    aoff[i] = row * KDIM + c16 * 4;
  }
  int a_wbyte = r0 * 128 + (((c16 >> 1) ^ (r0 & 7)) << 4) + (c16 & 1) * 8;
  int fb_n = t >> 1, fb_kh = (t & 1) * 32;

  f32x4 acc[4][4];
#pragma unroll
  for (int i = 0; i < 4; i++)
#pragma unroll
    for (int j = 0; j < 4; j++) acc[i][j] = (f32x4){0.f, 0.f, 0.f, 0.f};
  f32x4 va[8];

  auto loadA = [&](int kt) {
#pragma unroll
    for (int i = 0; i < 8; i++) va[i] = *(const f32x4*)(a + aoff[i] + kt * BK);
  };
  auto writeA = [&](int c) {
    char* db = (char*)lds_a2[c] + a_wbyte;
#pragma unroll
    for (int i = 0; i < 8; i++) {
      s16x4 v;
#pragma unroll
      for (int e = 0; e < 4; e++) v[e] = f2bf(va[i][e]);
      *(s16x4*)(db + i * 2048) = v;
    }
  };
  auto stageB = [&](int kt, int c) {
    const float* p = b + (size_t)g * KDIM * NDIM +
                     (size_t)(kt * BK + fb_kh) * NDIM + bn * 128 + fb_n;
    float vals[32];
#pragma unroll
    for (int i = 0; i < 32; i++) vals[i] = p[(size_t)i * NDIM];
    char* lb = (char*)lds_b2[c] + fb_n * 128;
#pragma unroll
    for (int i8 = 0; i8 < 4; i8++) {
      int slot = (fb_kh >> 3) + i8;
      s16x8 v;
#pragma unroll
      for (int e = 0; e < 8; e++) v[e] = f2bf(vals[i8 * 8 + e]);
      *(s16x8*)(lb + ((slot ^ (fb_n & 7)) << 4)) = v;
    }
  };
  auto compute = [&](int c) {
#pragma unroll
    for (int ks = 0; ks < 2; ks++) {
      s16x8 af[4], bf[4];
#pragma unroll
      for (int fm = 0; fm < 4; fm++) {
        int row = wm * 64 + fm * 16 + lr;
        int slot = (ks * 4 + q) ^ (row & 7);
        af[fm] =
            *(const s16x8*)((const char*)lds_a2[c] + row * 128 + slot * 16);
      }
#pragma unroll
      for (int fn = 0; fn < 4; fn++) {
        int n = wn * 64 + fn * 16 + lr;
        int slot = (ks * 4 + q) ^ (n & 7);
        bf[fn] = *(const s16x8*)((const char*)lds_b2[c] + n * 128 + slot * 16);
      }
#pragma unroll
      for (int fm = 0; fm < 4; fm++)
#pragma unroll
        for (int fn = 0; fn < 4; fn++)
          acc[fm][fn] = __builtin_amdgcn_mfma_f32_16x16x32_bf16(
              af[fm], bf[fn], acc[fm][fn], 0, 0, 0);
    }
  };

  loadA(0);
  stageB(0, 0);
  writeA(0);
  __syncthreads();
  for (int kt = 0; kt < KTILES; kt++) {
    int cur = kt & 1, nxt = cur ^ 1;
    bool more = (kt + 1 < KTILES);
    if (more) loadA(kt + 1);
    compute(cur);
    if (more) {
      stageB(kt + 1, nxt);
      writeA(nxt);
      __syncthreads();
    }
  }
  size_t orow0 = (size_t)(off + m_loc);
#pragma unroll
  for (int fm = 0; fm < 4; fm++) {
#pragma unroll
    for (int j = 0; j < 4; j++) {
      int rm = wm * 64 + fm * 16 + q * 4 + j;
      if (rm < valid) {
        float* orow = out + (orow0 + rm) * NDIM + bn * 128 + wn * 64 + lr;
#pragma unroll
        for (int fn = 0; fn < 4; fn++) orow[fn * 16] = acc[fm][fn][j];
      }
    }
  }
}

extern "C" void kernel_launch(void* const* d_in, const int* in_sizes, int n_in,
                              void* d_out, int out_size, void* d_ws,
                              size_t ws_size, hipStream_t stream) {
  const float* a = (const float*)d_in[0];
  const float* b = (const float*)d_in[1];
  const int* sizes = (const int*)d_in[2];
  const int* offs = (const int*)d_in[3];
  float* out = (float*)d_out;

  const size_t bt_bytes = (size_t)GCNT * KDIM * NDIM * 2;  // 64 MB
  if (ws_size >= bt_bytes) {
    bt_kernel<<<GCNT * 64, 256, 0, stream>>>(b, (char*)d_ws);
    gemm4<<<NBLK, 256, 0, stream>>>(a, (const char*)d_ws, sizes, offs, out);
  } else {
    gemm_fb<<<FB_NBLK, 256, 0, stream>>>(a, b, sizes, offs, out);
  }
}

// Round 13
// 332.750 us; speedup vs baseline: 2.2835x; 2.2835x over previous
//
#include <hip/hip_runtime.h>
#include <hip/hip_bf16.h>
#include <stdint.h>

#define T_ROWS 131072
#define GCNT   64
#define KDIM   1024
#define NDIM   512
#define BM     128
#define BN     128
#define BK     32
#define KTILES (KDIM / BK)     // 32
#define MT_MAX 1088            // upper bound on 128-row tiles (~1055 actual)
#define NBLK   (MT_MAX * 4)    // 4352 blocks, /8 = 544 (XCD swizzle exact)

typedef __attribute__((ext_vector_type(4))) float f32x4;
typedef __attribute__((ext_vector_type(8))) short s16x8;
typedef __attribute__((ext_vector_type(4))) short s16x4;
typedef __attribute__((address_space(3))) unsigned int lds_u32;
typedef const __attribute__((address_space(1))) unsigned int gbl_u32;

static __device__ __forceinline__ short f2bf(float f) {
  __hip_bfloat16 h = __float2bfloat16(f);
  return __builtin_bit_cast(short, h);
}

// ---------------------------------------------------------------------------
// Pre-pass: b [G][K][N] fp32 -> bt: per (g, nt128, kt32) 8KB bf16 images,
// layout [G][4][32][8192B]. Image byte for B[k][n] (k in [0,32), n in
// [0,128)):  n*64 + (((k>>3) ^ ((n>>1)&3))<<4) + (k&7)*2
// ((n>>1) XOR spreads 16-lane reads 2 rows/bank-quad = 2-way = free).
// ---------------------------------------------------------------------------
__global__ __launch_bounds__(256) void bt_kernel(const float* __restrict__ b,
                                                 char* __restrict__ bt) {
  __shared__ short lt[32 * 130];
  int bid = blockIdx.x;               // g*128 + nt*32 + kt
  int kt = bid & 31, nt = (bid >> 5) & 3, g = bid >> 7;
  int t = threadIdx.x;
  const float* src = b + ((size_t)(g * KDIM + kt * BK)) * NDIM + nt * 128;
#pragma unroll
  for (int i = 0; i < 16; i++) {
    int idx = i * 256 + t;
    int kk = idx >> 7, nn = idx & 127;
    lt[kk * 130 + nn] = f2bf(src[(size_t)kk * NDIM + nn]);
  }
  __syncthreads();
  char* dst = bt + ((size_t)bid << 13);
#pragma unroll
  for (int j = 0; j < 2; j++) {
    int chunk = j * 256 + t;            // 16B chunk index, 0..511
    int n = chunk >> 2;
    int s8 = (chunk & 3) ^ ((n >> 1) & 3);   // source k>>3
    s16x8 v;
#pragma unroll
    for (int i = 0; i < 8; i++) v[i] = lt[(s8 * 8 + i) * 130 + n];
    *(s16x8*)(dst + (size_t)chunk * 16) = v;
  }
}

// ---------------------------------------------------------------------------
// 16-wave/CU grouped GEMM: 128x128 tile, 4 waves, BK=32, 24KB LDS,
// __launch_bounds__(256,4) caps VGPR at 128 -> 4 blocks/CU (16 waves/CU).
// Cross-block TLP hides every per-block stall (r11 mechanism, doubled).
// A: single-buffered 8KB (end-of-tile barrier protects); B: dbuf 2x8KB DMA.
// Per tile kt (uniform kt=0..30; kt=31 peeled), r11's counted-wait chain:
//   stageB(kt+1->nxt) [2 DMA] | writeA(kt) [cvt auto-waits vmcnt(2):
//   retires A(kt)+B(kt), keeps B(kt+1) flying] | loadA(kt+1) [4 loads] |
//   lgkm0+bar | compute(cur) | bar.   No explicit vmcnt in the loop.
// ---------------------------------------------------------------------------
__global__ __launch_bounds__(256, 4) void gemm5(
    const float* __restrict__ a, const char* __restrict__ bt,
    const int* __restrict__ sizes, const int* __restrict__ offs,
    float* __restrict__ out) {
  __shared__ __align__(16) short lds_a[BM * BK];        // 8 KB, single
  __shared__ __align__(16) char lds_b[2][BN * BK * 2];  // 2 x 8 KB

  int bid0 = blockIdx.x;
  int bid = (bid0 & 7) * (NBLK / 8) + (bid0 >> 3);  // XCD-chunked swizzle
  int bn = bid & 3;      // bn fastest: 4 blocks sharing an A panel adjacent
  int tm = bid >> 2;

  int g = -1, m_loc = 0, base = 0;
#pragma unroll
  for (int i = 0; i < GCNT; i++) {
    int tg = ((sizes[i] + 127) & ~127) >> 7;
    if (tm >= base && tm < base + tg) { g = i; m_loc = (tm - base) << 7; }
    base += tg;
  }
  if (g < 0) return;
  int size = sizes[g], off = offs[g], valid = size - m_loc;

  int t = threadIdx.x, lane = t & 63, wid = t >> 6;
  int wm = wid >> 1, wn = wid & 1, lr = lane & 15, q = lane >> 4;

  // A staging: thread t owns row (t>>1), fp32 k-half h=(t&1)*16 (64B).
  int ar = t >> 1, ah = t & 1;
  {
    int row = off + m_loc + ar;
    if (row >= T_ROWS) row = T_ROWS - 1;  // junk rows masked at store
    ar = row;                             // absolute row
  }
  const float* abase = a + (size_t)ar * KDIM + ah * 16;
  // LDS write: row r=(t>>1) local, two slots q0=ah*2, q0+1
  int arl = t >> 1;
  int aslot0 = (ah * 2) ^ ((arl >> 1) & 3);
  int aslot1 = (ah * 2 + 1) ^ ((arl >> 1) & 3);
  char* awb = (char*)lds_a + arl * 64;

  const char* btimg = bt + ((size_t)((g << 7) + (bn << 5)) << 13);

  f32x4 acc[4][4];
#pragma unroll
  for (int i = 0; i < 4; i++)
#pragma unroll
    for (int j = 0; j < 4; j++) acc[i][j] = (f32x4){0.f, 0.f, 0.f, 0.f};
  f32x4 va[4];   // 16 fp32: k = ah*16 .. ah*16+15 of row ar

  auto loadA = [&](int kt) {
#pragma unroll
    for (int i = 0; i < 4; i++)
      va[i] = *(const f32x4*)(abase + kt * BK + i * 4);
  };
  auto writeA = [&]() {  // cvt auto-waits counted vmcnt on va
    s16x8 w0, w1;
#pragma unroll
    for (int e = 0; e < 4; e++) {
      w0[e] = f2bf(va[0][e]);
      w0[4 + e] = f2bf(va[1][e]);
      w1[e] = f2bf(va[2][e]);
      w1[4 + e] = f2bf(va[3][e]);
    }
    *(s16x8*)(awb + aslot0 * 16) = w0;
    *(s16x8*)(awb + aslot1 * 16) = w1;
  };
  auto stageB = [&](int kt, int c) {
#pragma unroll
    for (int i = 0; i < 2; i++) {
      int wc = wid * 2 + i;                 // wave-uniform 1KB chunk, 0..7
      int cc = wc * 64 + lane;
      const char* gsrc = btimg + ((size_t)kt << 13) + (size_t)cc * 16;
      __builtin_amdgcn_global_load_lds(
          (gbl_u32*)gsrc, (lds_u32*)((char*)lds_b[c] + wc * 1024), 16, 0, 0);
    }
  };
  auto compute = [&](int c) {
    s16x8 af[4], bf[4];
#pragma unroll
    for (int fm = 0; fm < 4; fm++) {
      int row = wm * 64 + fm * 16 + lr;
      int slot = q ^ ((row >> 1) & 3);
      af[fm] = *(const s16x8*)((const char*)lds_a + row * 64 + slot * 16);
    }
#pragma unroll
    for (int fn = 0; fn < 4; fn++) {
      int n = wn * 64 + fn * 16 + lr;
      int slot = q ^ ((n >> 1) & 3);
      bf[fn] = *(const s16x8*)((const char*)lds_b[c] + n * 64 + slot * 16);
    }
    __builtin_amdgcn_s_setprio(1);
#pragma unroll
    for (int fm = 0; fm < 4; fm++)
#pragma unroll
      for (int fn = 0; fn < 4; fn++)
        acc[fm][fn] = __builtin_amdgcn_mfma_f32_16x16x32_bf16(
            af[fm], bf[fn], acc[fm][fn], 0, 0, 0);
    __builtin_amdgcn_s_setprio(0);
  };

  // prologue: B(0) DMA first (oldest), then A(0) loads
  stageB(0, 0);
  __builtin_amdgcn_sched_barrier(0);
  loadA(0);

  // uniform loop kt = 0..30
  for (int kt = 0; kt < KTILES - 1; kt++) {
    int cur = kt & 1, nxt = cur ^ 1;
    stageB(kt + 1, nxt);                 // 2 DMA into the dead B buffer
    __builtin_amdgcn_sched_barrier(0);   // pin: B issues before A consumes
    writeA();                            // counted vmcnt: retires A(kt)+B(kt)
    loadA(kt + 1);                       // 4 loads, fly across compute
    asm volatile("s_waitcnt lgkmcnt(0)" ::: "memory");
    __builtin_amdgcn_s_barrier();        // publish lds_a + B(kt) ready
    compute(cur);
    __builtin_amdgcn_s_barrier();        // frees lds_a, lds_b[nxt]
  }
  // peeled kt = 31
  writeA();
  asm volatile("s_waitcnt lgkmcnt(0)" ::: "memory");
  __builtin_amdgcn_s_barrier();
  compute(1);

  // epilogue: D frag col = lane&15, row = (lane>>4)*4 + j; masked rows
  size_t orow0 = (size_t)(off + m_loc);
#pragma unroll
  for (int fm = 0; fm < 4; fm++) {
#pragma unroll
    for (int j = 0; j < 4; j++) {
      int rm = wm * 64 + fm * 16 + q * 4 + j;
      if (rm < valid) {
        float* orow = out + (orow0 + rm) * NDIM + bn * BN + wn * 64 + lr;
#pragma unroll
        for (int fn = 0; fn < 4; fn++) orow[fn * 16] = acc[fm][fn][j];
      }
    }
  }
}

// ---------------------------------------------------------------------------
// Fallback (no workspace): r11 2-phase 128x128 BK=64 kernel, B transposed
// in-kernel.
// ---------------------------------------------------------------------------
__global__ __launch_bounds__(256, 2) void gemm_fb(
    const float* __restrict__ a, const float* __restrict__ b,
    const int* __restrict__ sizes, const int* __restrict__ offs,
    float* __restrict__ out) {
  __shared__ __align__(16) short lds_a2[2][128 * 64];
  __shared__ __align__(16) char lds_b2[2][128 * 64 * 2];

  int bid0 = blockIdx.x;
  int bid = (bid0 & 7) * (NBLK / 8) + (bid0 >> 3);
  int bn = bid & 3;
  int tm = bid >> 2;

  int g = -1, m_loc = 0, base = 0;
#pragma unroll
  for (int i = 0; i < GCNT; i++) {
    int tg = ((sizes[i] + 127) & ~127) >> 7;
    if (tm >= base && tm < base + tg) { g = i; m_loc = (tm - base) << 7; }
    base += tg;
  }
  if (g < 0) return;
  int size = sizes[g], off = offs[g], valid = size - m_loc;

  int t = threadIdx.x, lane = t & 63, wid = t >> 6;
  int wm = wid >> 1, wn = wid & 1, lr = lane & 15, q = lane >> 4;

  int r0 = t >> 4, c16 = t & 15;
  int aoff[8];
#pragma unroll
  for (int i = 0; i < 8; i++) {
    int row = off + m_loc + i * 16 + r0;
    if (row >= T_ROWS) row = T_ROWS - 1;
    aoff[i] = row * KDIM + c16 * 4;
  }
  int a_wbyte = r0 * 128 + (((c16 >> 1) ^ (r0 & 7)) << 4) + (c16 & 1) * 8;
  int fb_n = t >> 1, fb_kh = (t & 1) * 32;

  f32x4 acc[4][4];
#pragma unroll
  for (int i = 0; i < 4; i++)
#pragma unroll
    for (int j = 0; j < 4; j++) acc[i][j] = (f32x4){0.f, 0.f, 0.f, 0.f};
  f32x4 va[8];

  auto loadA = [&](int kt) {
#pragma unroll
    for (int i = 0; i < 8; i++)
      va[i] = *(const f32x4*)(a + aoff[i] + kt * 64);
  };
  auto writeA = [&](int c) {
    char* db = (char*)lds_a2[c] + a_wbyte;
#pragma unroll
    for (int i = 0; i < 8; i++) {
      s16x4 v;
#pragma unroll
      for (int e = 0; e < 4; e++) v[e] = f2bf(va[i][e]);
      *(s16x4*)(db + i * 2048) = v;
    }
  };
  auto stageB = [&](int kt, int c) {
    const float* p = b + (size_t)g * KDIM * NDIM +
                     (size_t)(kt * 64 + fb_kh) * NDIM + bn * 128 + fb_n;
    float vals[32];
#pragma unroll
    for (int i = 0; i < 32; i++) vals[i] = p[(size_t)i * NDIM];
    char* lb = (char*)lds_b2[c] + fb_n * 128;
#pragma unroll
    for (int i8 = 0; i8 < 4; i8++) {
      int slot = (fb_kh >> 3) + i8;
      s16x8 v;
#pragma unroll
      for (int e = 0; e < 8; e++) v[e] = f2bf(vals[i8 * 8 + e]);
      *(s16x8*)(lb + ((slot ^ (fb_n & 7)) << 4)) = v;
    }
  };
  auto compute = [&](int c) {
#pragma unroll
    for (int ks = 0; ks < 2; ks++) {
      s16x8 af[4], bf[4];
#pragma unroll
      for (int fm = 0; fm < 4; fm++) {
        int row = wm * 64 + fm * 16 + lr;
        int slot = (ks * 4 + q) ^ (row & 7);
        af[fm] =
            *(const s16x8*)((const char*)lds_a2[c] + row * 128 + slot * 16);
      }
#pragma unroll
      for (int fn = 0; fn < 4; fn++) {
        int n = wn * 64 + fn * 16 + lr;
        int slot = (ks * 4 + q) ^ (n & 7);
        bf[fn] = *(const s16x8*)((const char*)lds_b2[c] + n * 128 + slot * 16);
      }
#pragma unroll
      for (int fm = 0; fm < 4; fm++)
#pragma unroll
        for (int fn = 0; fn < 4; fn++)
          acc[fm][fn] = __builtin_amdgcn_mfma_f32_16x16x32_bf16(
              af[fm], bf[fn], acc[fm][fn], 0, 0, 0);
    }
  };

  loadA(0);
  stageB(0, 0);
  writeA(0);
  __syncthreads();
  for (int kt = 0; kt < 16; kt++) {
    int cur = kt & 1, nxt = cur ^ 1;
    bool more = (kt + 1 < 16);
    if (more) loadA(kt + 1);
    compute(cur);
    if (more) {
      stageB(kt + 1, nxt);
      writeA(nxt);
      __syncthreads();
    }
  }
  size_t orow0 = (size_t)(off + m_loc);
#pragma unroll
  for (int fm = 0; fm < 4; fm++) {
#pragma unroll
    for (int j = 0; j < 4; j++) {
      int rm = wm * 64 + fm * 16 + q * 4 + j;
      if (rm < valid) {
        float* orow = out + (orow0 + rm) * NDIM + bn * 128 + wn * 64 + lr;
#pragma unroll
        for (int fn = 0; fn < 4; fn++) orow[fn * 16] = acc[fm][fn][j];
      }
    }
  }
}

extern "C" void kernel_launch(void* const* d_in, const int* in_sizes, int n_in,
                              void* d_out, int out_size, void* d_ws,
                              size_t ws_size, hipStream_t stream) {
  const float* a = (const float*)d_in[0];
  const float* b = (const float*)d_in[1];
  const int* sizes = (const int*)d_in[2];
  const int* offs = (const int*)d_in[3];
  float* out = (float*)d_out;

  const size_t bt_bytes = (size_t)GCNT * KDIM * NDIM * 2;  // 64 MB
  if (ws_size >= bt_bytes) {
    bt_kernel<<<GCNT * 128, 256, 0, stream>>>(b, (char*)d_ws);
    gemm5<<<NBLK, 256, 0, stream>>>(a, (const char*)d_ws, sizes, offs, out);
  } else {
    gemm_fb<<<NBLK, 256, 0, stream>>>(a, b, sizes, offs, out);
  }
}